// Round 1
// baseline (546.688 us; speedup 1.0000x reference)
//
#include <hip/hip_runtime.h>

// SX controlled gate on 16 qudits, dim=3, ctrl axis 2 (stride 3^13),
// obj axis 5 (stride 3^10). Gate matrix is real; action per flat index n:
//   d2 = digit(n, axis2), d5 = digit(n, axis5)
//   d2 != 1          -> out[n] = in[n]
//   d2 == 1, d5 == 0 -> out[n] = in[n + 3^10]
//   d2 == 1, d5 == 1 -> out[n] = in[n - 3^10]
//   d2 == 1, d5 == 2 -> out[n] = 0            (u overwrites the diagonal)
// Applied independently to qs_real -> out_re and qs_imag -> out_im.

#define P10 59049u           // 3^10, the contiguous chunk size
#define P16 43046721u        // 3^16, elements per array

__global__ __launch_bounds__(256) void sx_apply_kernel(
    const float* __restrict__ re_in, const float* __restrict__ im_in,
    float* __restrict__ re_out, float* __restrict__ im_out)
{
    unsigned tid = blockIdx.x * blockDim.x + threadIdx.x;
    unsigned n = tid * 4u;               // group base (4 consecutive elements)
    if (n >= P16) return;

    unsigned q = n / P10;                // chunk id (digits above axis 5... axes 0..5)
    unsigned r = n - q * P10;            // offset within chunk
    unsigned d5 = q % 3u;
    unsigned d2 = (q / 27u) % 3u;        // 3^13 = 3^10 * 27

    if (r <= P10 - 4u) {
        // all 4 elements share the same chunk -> uniform digits
        if (d2 != 1u) {
            float4 a = *(const float4*)(re_in + n);
            float4 b = *(const float4*)(im_in + n);
            *(float4*)(re_out + n) = a;
            *(float4*)(im_out + n) = b;
        } else if (d5 == 2u) {
            float4 z = make_float4(0.f, 0.f, 0.f, 0.f);
            *(float4*)(re_out + n) = z;
            *(float4*)(im_out + n) = z;
        } else {
            unsigned s = (d5 == 0u) ? (n + P10) : (n - P10);  // misaligned by 1 elem
            float4 a, b;
            a.x = re_in[s + 0u]; a.y = re_in[s + 1u];
            a.z = re_in[s + 2u]; a.w = re_in[s + 3u];
            b.x = im_in[s + 0u]; b.y = im_in[s + 1u];
            b.z = im_in[s + 2u]; b.w = im_in[s + 3u];
            *(float4*)(re_out + n) = a;
            *(float4*)(im_out + n) = b;
        }
    } else {
        // group straddles a chunk boundary (or is the final partial group)
        #pragma unroll
        for (unsigned j = 0; j < 4u; ++j) {
            unsigned m = n + j;
            if (m >= P16) break;
            unsigned qq = m / P10;
            unsigned dd5 = qq % 3u;
            unsigned dd2 = (qq / 27u) % 3u;
            float a, b;
            if (dd2 != 1u) {
                a = re_in[m]; b = im_in[m];
            } else if (dd5 == 2u) {
                a = 0.f; b = 0.f;
            } else {
                unsigned s = (dd5 == 0u) ? (m + P10) : (m - P10);
                a = re_in[s]; b = im_in[s];
            }
            re_out[m] = a;
            im_out[m] = b;
        }
    }
}

extern "C" void kernel_launch(void* const* d_in, const int* in_sizes, int n_in,
                              void* d_out, int out_size, void* d_ws, size_t ws_size,
                              hipStream_t stream)
{
    const float* re_in = (const float*)d_in[0];
    const float* im_in = (const float*)d_in[1];
    float* re_out = (float*)d_out;
    float* im_out = (float*)d_out + P16;

    unsigned groups = (P16 + 3u) / 4u;            // 10,761,681
    unsigned blocks = (groups + 255u) / 256u;     // 42,038
    sx_apply_kernel<<<blocks, 256, 0, stream>>>(re_in, im_in, re_out, im_out);
}